// Round 15
// baseline (45.771 us; speedup 1.0000x reference)
//
#include <hip/hip_runtime.h>

// Depthwise cross-correlation, B*C = 32768 planes: x[32][32] (*) k[8][8] -> out[25][25].
// softmax(weight) sums to 1.0 -> output == correlation; weight unused.
//
// Round-15: dual-column threads, MINIMAL delta from passing round 13.
// 13 threads/plane; thread j computes cols {2j, 2j+1} (j=12: col 24 only).
// Thread j reads row dwords j..j+4 as FIVE SCALAR b32 (exactly the reads of
// r13's threads ox=2j and ox=2j+1, which shared base ox>>1=j). Even col
// windows = d0..d3 (r13 sh=0 path verbatim); odd col = alignbit(d_{t+1},d_t,16)
// (r13 sh=16 path verbatim). No parity select / uint2 (r14's failing additions).
// Halves x LDS traffic per plane (125 -> 65 dwords/row) at identical dot2 count.
// Block=128, PPB=8: LDS 20.1 KB -> 8 blocks/CU, 16 waves/CU. kt[32] pinned
// with the r10 asm-touch (safe, VGPR 52 there) so the RA can't re-read taps.

#define NPLANES (128 * 256)
#define PPB 8
#define RST 18                      // row stride (dwords): 16 data + 2 pad
#define XP  592                     // plane stride: >= 576+max_shift(12), %4==0
#define KTB (PPB * XP)              // taps base (4736, %4==0)
#define KTS 36                      // taps plane stride
#define LDS_DW (KTB + PPB * KTS)    // 5024 dw = 20096 B -> 8 blocks/CU
#define OH 25
#define OW 25

__device__ __forceinline__ unsigned cvt_pk_bf16(float a, float b) {
    unsigned r;  // lo = bf16(a), hi = bf16(b)
    asm("v_cvt_pk_bf16_f32 %0, %1, %2" : "=v"(r) : "v"(a), "v"(b));
    return r;
}
__device__ __forceinline__ void dot2(float& acc, unsigned x2, unsigned k2) {
    asm("v_dot2_f32_bf16 %0, %1, %2, %0" : "+v"(acc) : "v"(x2), "v"(k2));
}
__device__ __forceinline__ unsigned funnel16(unsigned hi, unsigned lo) {
    unsigned r;  // ((hi:lo) >> 16)[31:0] : lo16 = hi(lo), hi16 = lo(hi)
    asm("v_alignbit_b32 %0, %1, %2, 16" : "=v"(r) : "v"(hi), "v"(lo));
    return r;
}

__device__ __forceinline__ int plane_shift(int pl) {
    const int m = pl % 3;           // bank de-correlation, even dwords
    return (m == 0) ? 0 : (m == 1) ? 12 : 8;
}

__global__ __launch_bounds__(128)
void dwxcorr_kernel(const float* __restrict__ x,
                    const float* __restrict__ kern,
                    float* __restrict__ out) {
    __shared__ unsigned ldsu[LDS_DW];
    const int tid = threadIdx.x;
    const int plane0 = blockIdx.x * PPB;   // NPLANES % PPB == 0 -> no tail

    // ---- Stage x: unit = (plane, row, half-row of 16 floats) -> 8 packed dwords ----
#pragma unroll
    for (int it = 0; it < 4; ++it) {
        const int u    = tid + it * 128;   // PPB*64 = 512 units
        const int pl   = u >> 6;
        const int rh   = u & 63;
        const int row  = rh >> 1;
        const int half = rh & 1;
        const float* g = x + (size_t)(plane0 + pl) * 1024 + row * 32 + half * 16;
        const float4 v0 = *reinterpret_cast<const float4*>(g + 0);
        const float4 v1 = *reinterpret_cast<const float4*>(g + 4);
        const float4 v2 = *reinterpret_cast<const float4*>(g + 8);
        const float4 v3 = *reinterpret_cast<const float4*>(g + 12);
        unsigned A[8];
        A[0] = cvt_pk_bf16(v0.x, v0.y); A[1] = cvt_pk_bf16(v0.z, v0.w);
        A[2] = cvt_pk_bf16(v1.x, v1.y); A[3] = cvt_pk_bf16(v1.z, v1.w);
        A[4] = cvt_pk_bf16(v2.x, v2.y); A[5] = cvt_pk_bf16(v2.z, v2.w);
        A[6] = cvt_pk_bf16(v3.x, v3.y); A[7] = cvt_pk_bf16(v3.z, v3.w);
        unsigned* base = &ldsu[pl * XP + plane_shift(pl) + row * RST + half * 8];
        *reinterpret_cast<uint2*>(base + 0) = make_uint2(A[0], A[1]);
        *reinterpret_cast<uint2*>(base + 2) = make_uint2(A[2], A[3]);
        *reinterpret_cast<uint2*>(base + 4) = make_uint2(A[4], A[5]);
        *reinterpret_cast<uint2*>(base + 6) = make_uint2(A[6], A[7]);
    }
    // ---- Stage taps: all 128 threads, one float4 -> 2 packed dwords each ----
    {
        const int pl = tid >> 4;           // PPB*16 == 128 units exactly
        const int o4 = tid & 15;
        const float4 v =
            *reinterpret_cast<const float4*>(kern + (size_t)(plane0 + pl) * 64 + o4 * 4);
        unsigned* kb = &ldsu[KTB + pl * KTS + o4 * 2];
        kb[0] = cvt_pk_bf16(v.x, v.y);
        kb[1] = cvt_pk_bf16(v.z, v.w);
    }
    __syncthreads();

    if (tid >= PPB * 13) return;     // 13 threads per plane (tids 104..127 idle)
    const int pb = tid / 13;
    const int j  = tid - pb * 13;    // pair base: cols 2j, 2j+1

    // ---- Taps -> 32 packed dwords, pinned in registers (r10-proven safe) ----
    unsigned kt[32];
    {
        const unsigned* kp = &ldsu[KTB + pb * KTS];
#pragma unroll
        for (int i = 0; i < 8; ++i) {
            const uint4 q = *reinterpret_cast<const uint4*>(kp + 4 * i);
            kt[4*i+0] = q.x; kt[4*i+1] = q.y; kt[4*i+2] = q.z; kt[4*i+3] = q.w;
        }
    }
#pragma unroll
    for (int i = 0; i < 32; ++i)
        asm volatile("" : "+v"(kt[i]));  // keep taps register-resident

    float accE[OH], accO[OH];
#pragma unroll
    for (int i = 0; i < OH; ++i) { accE[i] = 0.f; accO[i] = 0.f; }

    // Thread j: 5 scalar reads d0..d4 = row pairs j..j+4 (j=12: d4 = pad,
    // feeds only the dropped col 25). Identical reads to r13's ox=2j,2j+1.
    const unsigned* xb = &ldsu[pb * XP + plane_shift(pb) + j];
#pragma unroll
    for (int r = 0; r < 32; ++r) {
        const unsigned* rp = xb + r * RST;
        const unsigned d0 = rp[0], d1 = rp[1], d2 = rp[2], d3 = rp[3], d4 = rp[4];
        const unsigned v0 = funnel16(d1, d0);   // (x[2j+1], x[2j+2])
        const unsigned v1 = funnel16(d2, d1);
        const unsigned v2 = funnel16(d3, d2);
        const unsigned v3 = funnel16(d4, d3);
#pragma unroll
        for (int ky = 0; ky < 8; ++ky) {
            const int oy = r - ky;               // compile-time with full unroll
            if (oy >= 0 && oy < OH) {
                dot2(accE[oy], d0, kt[ky * 4 + 0]);
                dot2(accE[oy], d1, kt[ky * 4 + 1]);
                dot2(accE[oy], d2, kt[ky * 4 + 2]);
                dot2(accE[oy], d3, kt[ky * 4 + 3]);
                dot2(accO[oy], v0, kt[ky * 4 + 0]);
                dot2(accO[oy], v1, kt[ky * 4 + 1]);
                dot2(accO[oy], v2, kt[ky * 4 + 2]);
                dot2(accO[oy], v3, kt[ky * 4 + 3]);
            }
        }
    }

    // ---- Stores: cols 2j (always) and 2j+1 (j<12) ----
    float* op = out + (size_t)(plane0 + pb) * (OH * OW);
    const int c0 = 2 * j;
#pragma unroll
    for (int oy = 0; oy < OH; ++oy) {
        op[oy * OW + c0] = accE[oy];
        if (c0 + 1 < OW) op[oy * OW + c0 + 1] = accO[oy];
    }
}

extern "C" void kernel_launch(void* const* d_in, const int* in_sizes, int n_in,
                              void* d_out, int out_size, void* d_ws, size_t ws_size,
                              hipStream_t stream) {
    const float* x = (const float*)d_in[0];
    const float* k = (const float*)d_in[1];
    // d_in[2] (weight) unused: softmax weights sum to exactly 1.
    float* out = (float*)d_out;
    const int nblocks = NPLANES / PPB;   // 4096
    dwxcorr_kernel<<<nblocks, 128, 0, stream>>>(x, k, out);
}

// Round 16
// 44.641 us; speedup vs baseline: 1.0253x; 1.0253x over previous
//
#include <hip/hip_runtime.h>

// Depthwise cross-correlation, B*C = 32768 planes: x[32][32] (*) k[8][8] -> out[25][25].
// softmax(weight) sums to 1.0 -> output == correlation; weight unused.
//
// Base = round 13 (best passing, 43.8us): thread = (plane, ox), one output
// column; single packed-bf16 copy of x in LDS (RST=18, XP=592, plane shifts
// {0,12,8}); odd columns via v_alignbit; dot2 inner loop; PPB=8, block=256.
// Round-16 change: T14 async-stage SPLIT. Stage rows 0-15 -> barrier ->
// ISSUE global loads for rows 16-31 into regs (no wait) -> compute phase 1
// (x rows 0-15) overlapping the HBM latency -> cvt+ds_write rows 16-31
// (vmcnt wait lands here) -> barrier -> compute phase 2 (rows 16-31).
// Accumulators carry across the barrier; accumulation order per oy is
// unchanged (r ascending), so results are bit-identical to r13.

#define NPLANES (128 * 256)
#define PPB 8
#define RST 18                      // row stride (dwords): 16 data + 2 pad
#define XP  592                     // plane stride: >= 576+max_shift(12), %4==0
#define KTB (PPB * XP)              // taps base (4736, %4==0)
#define KTS 36                      // taps plane stride
#define LDS_DW (KTB + PPB * KTS)    // 5024 dw = 20096 B -> 8 blocks/CU
#define OH 25
#define OW 25

__device__ __forceinline__ unsigned cvt_pk_bf16(float a, float b) {
    unsigned r;  // lo = bf16(a), hi = bf16(b)
    asm("v_cvt_pk_bf16_f32 %0, %1, %2" : "=v"(r) : "v"(a), "v"(b));
    return r;
}
__device__ __forceinline__ void dot2(float& acc, unsigned x2, unsigned k2) {
    asm("v_dot2_f32_bf16 %0, %1, %2, %0" : "+v"(acc) : "v"(x2), "v"(k2));
}
__device__ __forceinline__ unsigned alignb(unsigned hi, unsigned lo, unsigned sh) {
    unsigned r;  // ((hi:lo) >> sh)[31:0]; sh=0 -> lo
    asm("v_alignbit_b32 %0, %1, %2, %3" : "=v"(r) : "v"(hi), "v"(lo), "v"(sh));
    return r;
}

__device__ __forceinline__ int plane_shift(int pl) {
    const int m = pl % 3;           // bank de-correlation, even dwords
    return (m == 0) ? 0 : (m == 1) ? 12 : 8;
}

__device__ __forceinline__ void pack_store_half(unsigned* ldsu, int pl, int row,
                                                int half, float4 v0, float4 v1,
                                                float4 v2, float4 v3) {
    unsigned A[8];
    A[0] = cvt_pk_bf16(v0.x, v0.y); A[1] = cvt_pk_bf16(v0.z, v0.w);
    A[2] = cvt_pk_bf16(v1.x, v1.y); A[3] = cvt_pk_bf16(v1.z, v1.w);
    A[4] = cvt_pk_bf16(v2.x, v2.y); A[5] = cvt_pk_bf16(v2.z, v2.w);
    A[6] = cvt_pk_bf16(v3.x, v3.y); A[7] = cvt_pk_bf16(v3.z, v3.w);
    unsigned* base = &ldsu[pl * XP + plane_shift(pl) + row * RST + half * 8];
    *reinterpret_cast<uint2*>(base + 0) = make_uint2(A[0], A[1]);
    *reinterpret_cast<uint2*>(base + 2) = make_uint2(A[2], A[3]);
    *reinterpret_cast<uint2*>(base + 4) = make_uint2(A[4], A[5]);
    *reinterpret_cast<uint2*>(base + 6) = make_uint2(A[6], A[7]);
}

__global__ __launch_bounds__(256)
void dwxcorr_kernel(const float* __restrict__ x,
                    const float* __restrict__ kern,
                    float* __restrict__ out) {
    __shared__ unsigned ldsu[LDS_DW];
    const int tid = threadIdx.x;
    const int plane0 = blockIdx.x * PPB;   // NPLANES % PPB == 0 -> no tail

    // Unit for this thread: 32 units/plane = 16 rows x 2 halves, 256 units total.
    const int upl  = tid >> 5;
    const int urh  = tid & 31;
    const int urow = urh >> 1;             // local row 0..15
    const int uhalf = urh & 1;

    // ---- Stage A: x rows 0..15 ----
    {
        const float* g = x + (size_t)(plane0 + upl) * 1024 + urow * 32 + uhalf * 16;
        const float4 v0 = *reinterpret_cast<const float4*>(g + 0);
        const float4 v1 = *reinterpret_cast<const float4*>(g + 4);
        const float4 v2 = *reinterpret_cast<const float4*>(g + 8);
        const float4 v3 = *reinterpret_cast<const float4*>(g + 12);
        pack_store_half(ldsu, upl, urow, uhalf, v0, v1, v2, v3);
    }
    // ---- Stage taps ----
    if (tid < PPB * 16) {
        const int pl = tid >> 4;
        const int o4 = tid & 15;
        const float4 v =
            *reinterpret_cast<const float4*>(kern + (size_t)(plane0 + pl) * 64 + o4 * 4);
        unsigned* kb = &ldsu[KTB + pl * KTS + o4 * 2];
        kb[0] = cvt_pk_bf16(v.x, v.y);
        kb[1] = cvt_pk_bf16(v.z, v.w);
    }
    __syncthreads();                        // barrier 1: rows 0-15 + taps ready

    // ---- Issue B loads: x rows 16..31 into registers, NO wait ----
    float4 b0, b1, b2, b3;
    {
        const float* g =
            x + (size_t)(plane0 + upl) * 1024 + (16 + urow) * 32 + uhalf * 16;
        b0 = *reinterpret_cast<const float4*>(g + 0);
        b1 = *reinterpret_cast<const float4*>(g + 4);
        b2 = *reinterpret_cast<const float4*>(g + 8);
        b3 = *reinterpret_cast<const float4*>(g + 12);
    }

    const bool isc = (tid < PPB * 25);      // 200 compute threads
    const int pb = isc ? (tid / 25) : 0;
    const int ox = isc ? (tid % 25) : 0;

    unsigned kt[32];
    float acc[OH];
    const unsigned sh = (ox & 1) * 16;
    const unsigned* xb = &ldsu[pb * XP + plane_shift(pb) + (ox >> 1)];

    if (isc) {
        const unsigned* kp = &ldsu[KTB + pb * KTS];
#pragma unroll
        for (int i = 0; i < 8; ++i) {
            const uint4 q = *reinterpret_cast<const uint4*>(kp + 4 * i);
            kt[4*i+0] = q.x; kt[4*i+1] = q.y; kt[4*i+2] = q.z; kt[4*i+3] = q.w;
        }
#pragma unroll
        for (int i = 0; i < OH; ++i) acc[i] = 0.f;

        // ---- Compute phase 1: x rows 0..15 (overlaps the B loads in flight) ----
#pragma unroll
        for (int r = 0; r < 16; ++r) {
            const unsigned* rp = xb + r * RST;
            const unsigned d0 = rp[0], d1 = rp[1], d2 = rp[2], d3 = rp[3], d4 = rp[4];
            const unsigned w0 = alignb(d1, d0, sh);
            const unsigned w1 = alignb(d2, d1, sh);
            const unsigned w2 = alignb(d3, d2, sh);
            const unsigned w3 = alignb(d4, d3, sh);
#pragma unroll
            for (int ky = 0; ky < 8; ++ky) {
                const int oy = r - ky;          // oy <= 15 < OH automatically
                if (oy >= 0) {
                    dot2(acc[oy], w0, kt[ky * 4 + 0]);
                    dot2(acc[oy], w1, kt[ky * 4 + 1]);
                    dot2(acc[oy], w2, kt[ky * 4 + 2]);
                    dot2(acc[oy], w3, kt[ky * 4 + 3]);
                }
            }
        }
    }

    // ---- Write B: first use of b0..b3 -> vmcnt wait lands here ----
    pack_store_half(ldsu, upl, 16 + urow, uhalf, b0, b1, b2, b3);
    __syncthreads();                        // barrier 2: rows 16-31 ready

    if (!isc) return;

    // ---- Compute phase 2: x rows 16..31 ----
#pragma unroll
    for (int r = 16; r < 32; ++r) {
        const unsigned* rp = xb + r * RST;
        const unsigned d0 = rp[0], d1 = rp[1], d2 = rp[2], d3 = rp[3], d4 = rp[4];
        const unsigned w0 = alignb(d1, d0, sh);
        const unsigned w1 = alignb(d2, d1, sh);
        const unsigned w2 = alignb(d3, d2, sh);
        const unsigned w3 = alignb(d4, d3, sh);
#pragma unroll
        for (int ky = 0; ky < 8; ++ky) {
            const int oy = r - ky;              // oy >= 8 >= 0 automatically
            if (oy < OH) {
                dot2(acc[oy], w0, kt[ky * 4 + 0]);
                dot2(acc[oy], w1, kt[ky * 4 + 1]);
                dot2(acc[oy], w2, kt[ky * 4 + 2]);
                dot2(acc[oy], w3, kt[ky * 4 + 3]);
            }
        }
    }

    // ---- Coalesced stores ----
    float* op = out + (size_t)(plane0 + pb) * (OH * OW) + ox;
#pragma unroll
    for (int oy = 0; oy < OH; ++oy) op[oy * OW] = acc[oy];
}

extern "C" void kernel_launch(void* const* d_in, const int* in_sizes, int n_in,
                              void* d_out, int out_size, void* d_ws, size_t ws_size,
                              hipStream_t stream) {
    const float* x = (const float*)d_in[0];
    const float* k = (const float*)d_in[1];
    // d_in[2] (weight) unused: softmax weights sum to exactly 1.
    float* out = (float*)d_out;
    const int nblocks = NPLANES / PPB;   // 4096
    dwxcorr_kernel<<<nblocks, 256, 0, stream>>>(x, k, out);
}